// Round 4
// baseline (671.522 us; speedup 1.0000x reference)
//
#include <hip/hip_runtime.h>

#define H_DIM 768
#define C_DIM 512
#define L_DIM 256
#define S_DIM 2048
#define B_DIM 16

#define IA_STRIDE 520   // 512 + 8: lane stride 1040B = 260 dw = 4 mod 32 banks
#define ATTN_STRIDE 264 // 256 + 8: lane stride 528B = 132 dw = 4 mod 32 banks

typedef __attribute__((ext_vector_type(8))) short short8;
typedef __attribute__((ext_vector_type(4))) float f32x4;
typedef __attribute__((ext_vector_type(4))) unsigned short ushort4v;
typedef __attribute__((ext_vector_type(2))) __fp16 half2v;   // matches cvt_pkrtz return type

#define MFMA_F16(a, b, c) __builtin_amdgcn_mfma_f32_16x16x32_f16((a), (b), (c), 0, 0, 0)

__device__ __forceinline__ unsigned short f2h(float f) {
    _Float16 h = (_Float16)f;
    return __builtin_bit_cast(unsigned short, h);
}
__device__ __forceinline__ float sigmoid_f(float x) { return 1.0f / (1.0f + __expf(-x)); }

// load 8 consecutive f32, convert to packed f16 frag via v_cvt_pkrtz (4 instrs)
__device__ __forceinline__ short8 cvt8(const float* p) {
    const float4* q = (const float4*)(const void*)p;
    float4 u = q[0], v = q[1];
    half2v h0 = __builtin_amdgcn_cvt_pkrtz(u.x, u.y);
    half2v h1 = __builtin_amdgcn_cvt_pkrtz(u.z, u.w);
    half2v h2 = __builtin_amdgcn_cvt_pkrtz(v.x, v.y);
    half2v h3 = __builtin_amdgcn_cvt_pkrtz(v.z, v.w);
    int4 pk = { __builtin_bit_cast(int, h0), __builtin_bit_cast(int, h1),
                __builtin_bit_cast(int, h2), __builtin_bit_cast(int, h3) };
    return __builtin_bit_cast(short8, pk);
}

// ---------------------------------------------------------------------------
// Kernel 0: convert Wi, Wia (f32 [C][H]) to f16 once. 4 elems/thread.
// ---------------------------------------------------------------------------
__global__ __launch_bounds__(256) void prep_weights(
    const float* __restrict__ Wi, const float* __restrict__ Wia,
    unsigned short* __restrict__ Wi_h, unsigned short* __restrict__ Wia_h)
{
    const int i = blockIdx.x * 256 + threadIdx.x;   // over (512*768)/4
    float4 a = ((const float4*)Wi)[i];
    float4 b = ((const float4*)Wia)[i];
    ushort4v ah = { f2h(a.x), f2h(a.y), f2h(a.z), f2h(a.w) };
    ushort4v bh = { f2h(b.x), f2h(b.y), f2h(b.z), f2h(b.w) };
    ((ushort4v*)Wi_h)[i]  = ah;
    ((ushort4v*)Wia_h)[i] = bh;
}

// ---------------------------------------------------------------------------
// Kernel 1: label-side GEMMs, tiled. Grid = 16 l-tiles x 8 c-tiles = 128
// blocks. Each block: stage 16 label rows in LDS, read a 64-col W slice ONCE
// (total W traffic 50 MB vs 800 MB for the naive per-label version).
//   lt_t[c*256 + l]   = f16( sigmoid(lab[l]·Wl[c] + bl[c]) )   (transposed)
//   la_ctx[l*512 + c] = f16( sigmoid(lab[l]·Wla[c] + bla[c]) * ctx[c] )
// ---------------------------------------------------------------------------
__global__ __launch_bounds__(256) void label_kernel(
    const float* __restrict__ lab,
    const float* __restrict__ Wl,  const float* __restrict__ bl,
    const float* __restrict__ Wla, const float* __restrict__ bla,
    const float* __restrict__ context,
    unsigned short* __restrict__ lt_t,
    unsigned short* __restrict__ la_ctx)
{
    __shared__ float labt[16 * H_DIM];
    const int t  = threadIdx.x;
    const int lt = blockIdx.x & 15;
    const int ct = blockIdx.x >> 4;
    const int l0 = lt * 16;
    const int c  = ct * 64 + (t & 63);
    const int lg = t >> 6;   // wave id: all 64 lanes share lg -> LDS broadcast
    {
        const float4* src = (const float4*)(const void*)(lab + l0 * H_DIM);
        float4* dst = (float4*)labt;
        for (int i = t; i < 16 * (H_DIM / 4); i += 256) dst[i] = src[i];
    }
    __syncthreads();
    const float4* wl  = (const float4*)(const void*)(Wl  + (size_t)c * H_DIM);
    const float4* wla = (const float4*)(const void*)(Wla + (size_t)c * H_DIM);
    const float4* lb  = (const float4*)labt;
    float s1[4] = {0.f, 0.f, 0.f, 0.f}, s2[4] = {0.f, 0.f, 0.f, 0.f};
    for (int k4 = 0; k4 < H_DIM / 4; ++k4) {
        float4 w1 = wl[k4], w2 = wla[k4];
#pragma unroll
        for (int j = 0; j < 4; ++j) {
            float4 lv = lb[(lg * 4 + j) * (H_DIM / 4) + k4];
            s1[j] += lv.x * w1.x + lv.y * w1.y + lv.z * w1.z + lv.w * w1.w;
            s2[j] += lv.x * w2.x + lv.y * w2.y + lv.z * w2.z + lv.w * w2.w;
        }
    }
    const float blv = bl[c], blav = bla[c], cv = context[c];
#pragma unroll
    for (int j = 0; j < 4; ++j) {
        const int l = l0 + lg * 4 + j;
        lt_t[c * L_DIM + l]   = f2h(sigmoid_f(s1[j] + blv));
        la_ctx[l * C_DIM + c] = f2h(sigmoid_f(s2[j] + blav) * cv);
    }
}

// ---------------------------------------------------------------------------
// Kernel 2: fused main. One block = 32 rows of [B*S]. 4 waves.
// Phase 1: ia = sigmoid(x@Wia^T+bia) -> LDS (acc[2][8] only: 64 acc VGPRs,
//          so __launch_bounds__(256,4) fits VGPR<=128 -> 4 blocks/CU).
// Phase 2: logits = ia @ la_ctx^T.  Phase 3: softmax (unnorm, keep 1/sum).
// Phase 4: weighted = attn @ lt.    Phase 5: it-GEMM recomputed in nt-pairs
//          (x tile is L2-hot) fused with the fusion reduction + atomics.
// MFMA 16x16x32: A frag = A[m=lane&15][k=quad*8+j], B frag = B[n=lane&15][k],
// C/D: col = lane&15, row = quad*4 + reg.
// ---------------------------------------------------------------------------
__global__ __launch_bounds__(256, 4) void fused_main(
    const float* __restrict__ x,
    const float* __restrict__ bi,
    const float* __restrict__ bia,
    const unsigned short* __restrict__ Wi_h,    // f16 [C][H]
    const unsigned short* __restrict__ Wia_h,   // f16 [C][H]
    const unsigned short* __restrict__ lt_t,    // f16 [C][L]
    const unsigned short* __restrict__ la_ctx,  // f16 [L][C]
    float* __restrict__ fusion)                 // f32 [B][C]
{
    __shared__ unsigned short lds_buf[32 * IA_STRIDE]; // ia [32][520]; head reused as attn [32][264]
    __shared__ float rowscratch[4 * 32];
    __shared__ float inv_lds[32];

    const int tid  = threadIdx.x;
    const int wave = tid >> 6;
    const int lane = tid & 63;
    const int quad = lane >> 4;
    const int c16  = lane & 15;

    const int row0 = blockIdx.x * 32;
    const int b    = row0 >> 11;   // / 2048

    const f32x4 z4 = {0.f, 0.f, 0.f, 0.f};
    const int n0 = wave * 128;     // C-column split for ia / it / weighted

    // ========== Phase 1: ia = x@Wia^T (K=768), sigmoid -> LDS =============
    f32x4 acc[2][8];
#pragma unroll
    for (int mt = 0; mt < 2; ++mt)
#pragma unroll
        for (int nt = 0; nt < 8; ++nt) acc[mt][nt] = z4;
    {
        const float* xb = x + (size_t)(row0 + c16) * H_DIM + quad * 8;
        const unsigned short* wa = Wia_h + (size_t)(n0 + c16) * H_DIM + quad * 8;
        for (int kk = 0; kk < H_DIM; kk += 32) {
            short8 a0 = cvt8(xb + kk);
            short8 a1 = cvt8(xb + 16 * H_DIM + kk);
#pragma unroll
            for (int nt = 0; nt < 8; ++nt) {
                short8 ba = *(const short8*)(const void*)(wa + nt * 16 * H_DIM + kk);
                acc[0][nt] = MFMA_F16(a0, ba, acc[0][nt]);
                acc[1][nt] = MFMA_F16(a1, ba, acc[1][nt]);
            }
        }
    }
#pragma unroll
    for (int nt = 0; nt < 8; ++nt) {
        const int col = n0 + nt * 16 + c16;
        const float bv = bia[col];
#pragma unroll
        for (int mt = 0; mt < 2; ++mt)
#pragma unroll
            for (int r = 0; r < 4; ++r) {
                const int row = mt * 16 + quad * 4 + r;
                lds_buf[row * IA_STRIDE + col] = f2h(sigmoid_f(acc[mt][nt][r] + bv));
            }
    }
    __syncthreads();

    // ========== Phase 2: logits = ia @ la_ctx^T (K=512) ===================
    const int n0l = wave * 64;   // L-column split
    f32x4 accl[2][4];
#pragma unroll
    for (int mt = 0; mt < 2; ++mt)
#pragma unroll
        for (int nt = 0; nt < 4; ++nt) accl[mt][nt] = z4;
    {
        const unsigned short* ab = lds_buf + c16 * IA_STRIDE + quad * 8;
        const unsigned short* bb = la_ctx + (size_t)(n0l + c16) * C_DIM + quad * 8;
        for (int kk = 0; kk < C_DIM; kk += 32) {
            short8 a0 = *(const short8*)(const void*)(ab + kk);
            short8 a1 = *(const short8*)(const void*)(ab + 16 * IA_STRIDE + kk);
#pragma unroll
            for (int nt = 0; nt < 4; ++nt) {
                short8 bfr = *(const short8*)(const void*)(bb + nt * 16 * C_DIM + kk);
                accl[0][nt] = MFMA_F16(a0, bfr, accl[0][nt]);
                accl[1][nt] = MFMA_F16(a1, bfr, accl[1][nt]);
            }
        }
    }
    __syncthreads();   // all ia reads complete; lds_buf reusable

    // ========== Phase 3: softmax over L (unnormalized; keep 1/sum) ========
    float rmax[2][4];
#pragma unroll
    for (int mt = 0; mt < 2; ++mt)
#pragma unroll
        for (int r = 0; r < 4; ++r) {
            float m = accl[mt][0][r];
#pragma unroll
            for (int nt = 1; nt < 4; ++nt) m = fmaxf(m, accl[mt][nt][r]);
#pragma unroll
            for (int off = 1; off < 16; off <<= 1) m = fmaxf(m, __shfl_xor(m, off, 64));
            rmax[mt][r] = m;
        }
    if (c16 == 0) {
#pragma unroll
        for (int mt = 0; mt < 2; ++mt)
#pragma unroll
            for (int r = 0; r < 4; ++r)
                rowscratch[wave * 32 + mt * 16 + quad * 4 + r] = rmax[mt][r];
    }
    __syncthreads();
    float rsum[2][4];
#pragma unroll
    for (int mt = 0; mt < 2; ++mt)
#pragma unroll
        for (int r = 0; r < 4; ++r) {
            const int row = mt * 16 + quad * 4 + r;
            float gm = rowscratch[row];
#pragma unroll
            for (int w = 1; w < 4; ++w) gm = fmaxf(gm, rowscratch[w * 32 + row]);
            float s = 0.f;
#pragma unroll
            for (int nt = 0; nt < 4; ++nt) {
                float e = __expf(accl[mt][nt][r] - gm);
                accl[mt][nt][r] = e;
                s += e;
            }
#pragma unroll
            for (int off = 1; off < 16; off <<= 1) s += __shfl_xor(s, off, 64);
            rsum[mt][r] = s;
        }
    __syncthreads();   // maxima consumed
    if (c16 == 0) {
#pragma unroll
        for (int mt = 0; mt < 2; ++mt)
#pragma unroll
            for (int r = 0; r < 4; ++r)
                rowscratch[wave * 32 + mt * 16 + quad * 4 + r] = rsum[mt][r];
    }
    __syncthreads();
#pragma unroll
    for (int mt = 0; mt < 2; ++mt)
#pragma unroll
        for (int r = 0; r < 4; ++r) {
            const int row = mt * 16 + quad * 4 + r;
            const float st = rowscratch[row] + rowscratch[32 + row]
                           + rowscratch[64 + row] + rowscratch[96 + row];
            if (wave == 0 && c16 == 0) inv_lds[row] = 1.0f / st;
            // unnormalized attn e-values, f16, [32][ATTN_STRIDE]
#pragma unroll
            for (int nt = 0; nt < 4; ++nt)
                lds_buf[row * ATTN_STRIDE + n0l + nt * 16 + c16] = f2h(accl[mt][nt][r]);
        }
    __syncthreads();

    // ========== Phase 4: weighted = attn @ lt (via lt_t), K=256 ===========
    f32x4 accw[2][8];
#pragma unroll
    for (int mt = 0; mt < 2; ++mt)
#pragma unroll
        for (int nt = 0; nt < 8; ++nt) accw[mt][nt] = z4;
    {
        const unsigned short* ab = lds_buf + c16 * ATTN_STRIDE + quad * 8;
        const unsigned short* bb = lt_t + (size_t)(n0 + c16) * L_DIM + quad * 8;
        for (int kk = 0; kk < L_DIM; kk += 32) {
            short8 a0 = *(const short8*)(const void*)(ab + kk);
            short8 a1 = *(const short8*)(const void*)(ab + 16 * ATTN_STRIDE + kk);
#pragma unroll
            for (int nt = 0; nt < 8; ++nt) {
                short8 bfr = *(const short8*)(const void*)(bb + nt * 16 * L_DIM + kk);
                accw[0][nt] = MFMA_F16(a0, bfr, accw[0][nt]);
                accw[1][nt] = MFMA_F16(a1, bfr, accw[1][nt]);
            }
        }
    }

    // ========== Phase 5: it-GEMM (recomputed, nt-pairs) + fusion ==========
    float invr[2][4];
#pragma unroll
    for (int mt = 0; mt < 2; ++mt)
#pragma unroll
        for (int r = 0; r < 4; ++r) invr[mt][r] = inv_lds[mt * 16 + quad * 4 + r];

    const float* xb = x + (size_t)(row0 + c16) * H_DIM + quad * 8;
#pragma unroll
    for (int nth = 0; nth < 4; ++nth) {
        f32x4 acci[2][2];
        acci[0][0] = z4; acci[0][1] = z4; acci[1][0] = z4; acci[1][1] = z4;
        const unsigned short* wi = Wi_h + (size_t)(n0 + nth * 32 + c16) * H_DIM + quad * 8;
        for (int kk = 0; kk < H_DIM; kk += 32) {
            short8 a0 = cvt8(xb + kk);
            short8 a1 = cvt8(xb + 16 * H_DIM + kk);
#pragma unroll
            for (int p = 0; p < 2; ++p) {
                short8 bw = *(const short8*)(const void*)(wi + p * 16 * H_DIM + kk);
                acci[0][p] = MFMA_F16(a0, bw, acci[0][p]);
                acci[1][p] = MFMA_F16(a1, bw, acci[1][p]);
            }
        }
#pragma unroll
        for (int p = 0; p < 2; ++p) {
            const int nt = nth * 2 + p;
            const int col = n0 + nt * 16 + c16;
            const float bv = bi[col];
            float s = 0.f;
#pragma unroll
            for (int mt = 0; mt < 2; ++mt)
#pragma unroll
                for (int r = 0; r < 4; ++r)
                    s += accw[mt][nt][r] * sigmoid_f(acci[mt][p][r] + bv) * invr[mt][r];
            s += __shfl_xor(s, 16, 64);
            s += __shfl_xor(s, 32, 64);
            if (lane < 16) atomicAdd(&fusion[b * C_DIM + col], s);
        }
    }
}

// ---------------------------------------------------------------------------
// Kernel 3: out[b][h] = sum_c fusion[b][c] * Wp[h][c]   (f32 out)
// ---------------------------------------------------------------------------
__global__ __launch_bounds__(256) void out_kernel(
    const float* __restrict__ fusion,
    const float* __restrict__ Wp,
    float* __restrict__ out)
{
    const int idx = blockIdx.x * 256 + threadIdx.x;
    const int bb = idx / H_DIM;
    const int h  = idx - bb * H_DIM;
    const float4* wp = (const float4*)(const void*)(Wp + (size_t)h * C_DIM);
    const float* f = fusion + bb * C_DIM;
    float s = 0.f;
    for (int k4 = 0; k4 < C_DIM / 4; ++k4) {
        float4 wv = wp[k4];
        s += f[k4 * 4 + 0] * wv.x + f[k4 * 4 + 1] * wv.y
           + f[k4 * 4 + 2] * wv.z + f[k4 * 4 + 3] * wv.w;
    }
    out[idx] = s;
}

extern "C" void kernel_launch(void* const* d_in, const int* in_sizes, int n_in,
                              void* d_out, int out_size, void* d_ws, size_t ws_size,
                              hipStream_t stream)
{
    const float* x    = (const float*)d_in[0];
    const float* lab  = (const float*)d_in[1];
    const float* Wi   = (const float*)d_in[2];
    const float* bi   = (const float*)d_in[3];
    const float* Wl   = (const float*)d_in[4];
    const float* bl   = (const float*)d_in[5];
    const float* Wia  = (const float*)d_in[6];
    const float* bia  = (const float*)d_in[7];
    const float* Wla  = (const float*)d_in[8];
    const float* bla  = (const float*)d_in[9];
    const float* ctx  = (const float*)d_in[10];
    const float* Wp   = (const float*)d_in[11];

    char* ws = (char*)d_ws;
    unsigned short* lt_t   = (unsigned short*)(ws);              // f16 [512][256] = 256 KB
    unsigned short* la_ctx = (unsigned short*)(ws + 262144);     // f16 [256][512] = 256 KB
    unsigned short* Wi_h   = (unsigned short*)(ws + 524288);     // f16 [512][768] = 768 KB
    unsigned short* Wia_h  = (unsigned short*)(ws + 1310720);    // f16 [512][768] = 768 KB
    float* fusion          = (float*)(ws + 2097152);             // f32 [16][512]  =  32 KB

    (void)hipMemsetAsync(fusion, 0, B_DIM * C_DIM * sizeof(float), stream);
    prep_weights<<<(C_DIM * H_DIM) / (4 * 256), 256, 0, stream>>>(Wi, Wia, Wi_h, Wia_h);
    label_kernel<<<128, 256, 0, stream>>>(lab, Wl, bl, Wla, bla, ctx, lt_t, la_ctx);
    fused_main<<<(B_DIM * S_DIM) / 32, 256, 0, stream>>>(x, bi, bia, Wi_h, Wia_h, lt_t, la_ctx, fusion);
    out_kernel<<<(B_DIM * H_DIM) / 256, 256, 0, stream>>>(fusion, Wp, (float*)d_out);
}

// Round 5
// 454.863 us; speedup vs baseline: 1.4763x; 1.4763x over previous
//
#include <hip/hip_runtime.h>

#define H_DIM 768
#define C_DIM 512
#define L_DIM 256
#define S_DIM 2048
#define B_DIM 16

#define IA_STRIDE 520   // 512 + 8: lane stride 1040B = 260 dw = 4 mod 32 banks
#define ATTN_STRIDE 264 // 256 + 8: lane stride 528B = 132 dw = 4 mod 32 banks

typedef __attribute__((ext_vector_type(8))) short short8;
typedef __attribute__((ext_vector_type(4))) float f32x4;
typedef __attribute__((ext_vector_type(2))) __fp16 half2v;   // cvt_pkrtz return type

#define MFMA_F16(a, b, c) __builtin_amdgcn_mfma_f32_16x16x32_f16((a), (b), (c), 0, 0, 0)

__device__ __forceinline__ unsigned short f2h(float f) {
    _Float16 h = (_Float16)f;
    return __builtin_bit_cast(unsigned short, h);
}
__device__ __forceinline__ float sigmoid_f(float x) { return 1.0f / (1.0f + __expf(-x)); }

// load 8 consecutive f32, convert to packed f16 frag via v_cvt_pkrtz
__device__ __forceinline__ short8 cvt8(const float* p) {
    const float4* q = (const float4*)(const void*)p;
    float4 u = q[0], v = q[1];
    half2v h0 = __builtin_amdgcn_cvt_pkrtz(u.x, u.y);
    half2v h1 = __builtin_amdgcn_cvt_pkrtz(u.z, u.w);
    half2v h2 = __builtin_amdgcn_cvt_pkrtz(v.x, v.y);
    half2v h3 = __builtin_amdgcn_cvt_pkrtz(v.z, v.w);
    int4 pk = { __builtin_bit_cast(int, h0), __builtin_bit_cast(int, h1),
                __builtin_bit_cast(int, h2), __builtin_bit_cast(int, h3) };
    return __builtin_bit_cast(short8, pk);
}

// ---------------------------------------------------------------------------
// Frag layout for an MFMA-B operand M[n][k] (n rows of 16, k in chunks of 32):
//   frag f = nt*KT + kt ; elem idx = (f*64 + lane)*8 + j
//   where lane = (n&15) | (((k>>3)&3)<<4), j = k&7.
// One wave B-frag load = 64 lanes x 16 B = 1 KB fully contiguous.
// ---------------------------------------------------------------------------

// Kernel 0: repack Wi, Wia (f32 [C][H]) into frag-f16 layout.
// 2 matrices x 32 ct x 24 kt x 64 lanes = 98304 threads.
__global__ __launch_bounds__(256) void prep_w(
    const float* __restrict__ Wi, const float* __restrict__ Wia,
    unsigned short* __restrict__ Wi_f, unsigned short* __restrict__ Wia_f)
{
    const int tid = blockIdx.x * 256 + threadIdx.x;
    const int m   = tid >= 49152;
    const int idx = tid - (m ? 49152 : 0);
    const int ct   = idx / 1536;          // 0..31
    const int rem  = idx - ct * 1536;
    const int kt   = rem >> 6;            // 0..23
    const int lane = rem & 63;
    const int row  = ct * 16 + (lane & 15);
    const int kcol = kt * 32 + (lane >> 4) * 8;
    const float* src = (m ? Wia : Wi) + (size_t)row * H_DIM + kcol;
    short8 v = cvt8(src);
    unsigned short* dst = (m ? Wia_f : Wi_f) + ((size_t)(ct * 24 + kt) * 64 + lane) * 8;
    *(short8*)(void*)dst = v;
}

// ---------------------------------------------------------------------------
// Kernel 1: label-side joint MFMA GEMM (0.86 GF total).
// Grid 32 = 8 c-tiles(64 cols) x 4 label-quarters(64 labels). Wave: 16 cols,
// 4 m-tiles, K=768. Epilogue scatter-writes la_f / lt_f in frag layout.
// ---------------------------------------------------------------------------
__global__ __launch_bounds__(256) void label_mfma(
    const float* __restrict__ lab,
    const float* __restrict__ Wl,  const float* __restrict__ bl,
    const float* __restrict__ Wla, const float* __restrict__ bla,
    const float* __restrict__ ctx,
    unsigned short* __restrict__ la_f,   // B-frag for logits: n=l (16 tiles), k=c (16 kts)
    unsigned short* __restrict__ lt_f)   // B-frag for weighted: n=c (32 tiles), k=l (8 kts)
{
    const int tid  = threadIdx.x;
    const int wave = tid >> 6;
    const int lane = tid & 63;
    const int quad = lane >> 4;
    const int c16  = lane & 15;
    const int ct2  = blockIdx.x & 7;
    const int mh   = blockIdx.x >> 3;    // 0..3
    const int n0   = ct2 * 64 + wave * 16;
    const int l0   = mh * 64;

    const f32x4 z4 = {0.f, 0.f, 0.f, 0.f};
    f32x4 a1[4], a2[4];
#pragma unroll
    for (int mt = 0; mt < 4; ++mt) { a1[mt] = z4; a2[mt] = z4; }

    const float* lb  = lab + (size_t)(l0 + c16) * H_DIM + quad * 8;
    const float* wl  = Wl  + (size_t)(n0 + c16) * H_DIM + quad * 8;
    const float* wla = Wla + (size_t)(n0 + c16) * H_DIM + quad * 8;
    for (int kt = 0; kt < 24; ++kt) {
        const int kk = kt * 32;
        short8 b1 = cvt8(wl + kk);
        short8 b2 = cvt8(wla + kk);
#pragma unroll
        for (int mt = 0; mt < 4; ++mt) {
            short8 a = cvt8(lb + mt * 16 * H_DIM + kk);
            a1[mt] = MFMA_F16(a, b1, a1[mt]);
            a2[mt] = MFMA_F16(a, b2, a2[mt]);
        }
    }
    const int c = n0 + c16;
    const float blv = bl[c], blav = bla[c], cv = ctx[c];
#pragma unroll
    for (int mt = 0; mt < 4; ++mt)
#pragma unroll
        for (int r = 0; r < 4; ++r) {
            const int l = l0 + mt * 16 + quad * 4 + r;
            const float ltv = sigmoid_f(a1[mt][r] + blv);
            const float lav = sigmoid_f(a2[mt][r] + blav) * cv;
            lt_f[((size_t)((c >> 4) * 8 + (l >> 5)) * 64 + ((c & 15) | (((l >> 3) & 3) << 4))) * 8 + (l & 7)] = f2h(ltv);
            la_f[((size_t)((l >> 4) * 16 + (c >> 5)) * 64 + ((l & 15) | (((c >> 3) & 3) << 4))) * 8 + (c & 7)] = f2h(lav);
        }
}

// ---------------------------------------------------------------------------
// Kernel 2: fused main. One block = 32 rows of [B*S]. 4 waves.
// Phase 1: JOINT ia+it GEMM over x (x read once; acci stays in regs to phase5).
//   All B-frags are frag-packed: one contiguous 1 KB load per wave per frag.
// Phase 2: logits = ia @ la^T.  Phase 3: softmax (unnorm, keep 1/sum).
// Phase 4: weighted = attn @ lt. Phase 5: fusion reduction + atomics.
// MFMA 16x16x32: A frag = A[m=lane&15][k=quad*8+j]; C/D: col=lane&15,
// row = quad*4 + reg.
// ---------------------------------------------------------------------------
__global__ __launch_bounds__(256) void fused_main(
    const float* __restrict__ x,
    const float* __restrict__ bi,
    const float* __restrict__ bia,
    const unsigned short* __restrict__ Wi_f,    // frag f16, 32 ct x 24 kt
    const unsigned short* __restrict__ Wia_f,   // frag f16
    const unsigned short* __restrict__ lt_f,    // frag f16, 32 ct x 8 kt
    const unsigned short* __restrict__ la_f,    // frag f16, 16 lt x 16 kt
    float* __restrict__ fusion)                 // f32 [B][C]
{
    __shared__ unsigned short lds_buf[32 * IA_STRIDE]; // ia [32][520]; head reused as attn [32][264]
    __shared__ float rowscratch[4 * 32];
    __shared__ float inv_lds[32];

    const int tid  = threadIdx.x;
    const int wave = tid >> 6;
    const int lane = tid & 63;
    const int quad = lane >> 4;
    const int c16  = lane & 15;

    const int row0 = blockIdx.x * 32;
    const int b    = row0 >> 11;   // / 2048

    const f32x4 z4 = {0.f, 0.f, 0.f, 0.f};
    const int n0 = wave * 128;     // C-column split

    // ========== Phase 1: joint  ia = x@Wia^T, it = x@Wi^T (K=768) =========
    f32x4 acc[2][8], acci[2][8];
#pragma unroll
    for (int mt = 0; mt < 2; ++mt)
#pragma unroll
        for (int nt = 0; nt < 8; ++nt) { acc[mt][nt] = z4; acci[mt][nt] = z4; }
    {
        const float* xb = x + (size_t)(row0 + c16) * H_DIM + quad * 8;
        const short8* wa8 = (const short8*)(const void*)Wia_f + (size_t)wave * 192 * 64 + lane;
        const short8* wi8 = (const short8*)(const void*)Wi_f  + (size_t)wave * 192 * 64 + lane;
        for (int kt = 0; kt < 24; ++kt) {
            short8 a0 = cvt8(xb + kt * 32);
            short8 a1 = cvt8(xb + 16 * H_DIM + kt * 32);
#pragma unroll
            for (int nt = 0; nt < 8; ++nt) {
                short8 ba = wa8[(nt * 24 + kt) * 64];
                short8 bw = wi8[(nt * 24 + kt) * 64];
                acc[0][nt]  = MFMA_F16(a0, ba, acc[0][nt]);
                acc[1][nt]  = MFMA_F16(a1, ba, acc[1][nt]);
                acci[0][nt] = MFMA_F16(a0, bw, acci[0][nt]);
                acci[1][nt] = MFMA_F16(a1, bw, acci[1][nt]);
            }
        }
    }
    // sigmoid(ia + bia) -> LDS f16 [32][IA_STRIDE]
#pragma unroll
    for (int nt = 0; nt < 8; ++nt) {
        const int col = n0 + nt * 16 + c16;
        const float bv = bia[col];
#pragma unroll
        for (int mt = 0; mt < 2; ++mt)
#pragma unroll
            for (int r = 0; r < 4; ++r) {
                const int row = mt * 16 + quad * 4 + r;
                lds_buf[row * IA_STRIDE + col] = f2h(sigmoid_f(acc[mt][nt][r] + bv));
            }
    }
    __syncthreads();

    // ========== Phase 2: logits = ia @ la^T (K=512) =======================
    const int n0l = wave * 64;   // L-column split
    f32x4 accl[2][4];
#pragma unroll
    for (int mt = 0; mt < 2; ++mt)
#pragma unroll
        for (int nt = 0; nt < 4; ++nt) accl[mt][nt] = z4;
    {
        const unsigned short* ab = lds_buf + c16 * IA_STRIDE + quad * 8;
        const short8* la8 = (const short8*)(const void*)la_f + lane;
        for (int kt = 0; kt < 16; ++kt) {
            const int kk = kt * 32;
            short8 a0 = *(const short8*)(const void*)(ab + kk);
            short8 a1 = *(const short8*)(const void*)(ab + 16 * IA_STRIDE + kk);
#pragma unroll
            for (int nt = 0; nt < 4; ++nt) {
                short8 bfr = la8[(((wave * 4 + nt) * 16) + kt) * 64];
                accl[0][nt] = MFMA_F16(a0, bfr, accl[0][nt]);
                accl[1][nt] = MFMA_F16(a1, bfr, accl[1][nt]);
            }
        }
    }
    __syncthreads();   // all ia reads complete; lds_buf reusable

    // ========== Phase 3: softmax over L (unnormalized; keep 1/sum) ========
    float rmax[2][4];
#pragma unroll
    for (int mt = 0; mt < 2; ++mt)
#pragma unroll
        for (int r = 0; r < 4; ++r) {
            float m = accl[mt][0][r];
#pragma unroll
            for (int nt = 1; nt < 4; ++nt) m = fmaxf(m, accl[mt][nt][r]);
#pragma unroll
            for (int off = 1; off < 16; off <<= 1) m = fmaxf(m, __shfl_xor(m, off, 64));
            rmax[mt][r] = m;
        }
    if (c16 == 0) {
#pragma unroll
        for (int mt = 0; mt < 2; ++mt)
#pragma unroll
            for (int r = 0; r < 4; ++r)
                rowscratch[wave * 32 + mt * 16 + quad * 4 + r] = rmax[mt][r];
    }
    __syncthreads();
    float rsum[2][4];
#pragma unroll
    for (int mt = 0; mt < 2; ++mt)
#pragma unroll
        for (int r = 0; r < 4; ++r) {
            const int row = mt * 16 + quad * 4 + r;
            float gm = rowscratch[row];
#pragma unroll
            for (int w = 1; w < 4; ++w) gm = fmaxf(gm, rowscratch[w * 32 + row]);
            float s = 0.f;
#pragma unroll
            for (int nt = 0; nt < 4; ++nt) {
                float e = __expf(accl[mt][nt][r] - gm);
                accl[mt][nt][r] = e;
                s += e;
            }
#pragma unroll
            for (int off = 1; off < 16; off <<= 1) s += __shfl_xor(s, off, 64);
            rsum[mt][r] = s;
        }
    __syncthreads();   // maxima consumed
    if (c16 == 0) {
#pragma unroll
        for (int mt = 0; mt < 2; ++mt)
#pragma unroll
            for (int r = 0; r < 4; ++r)
                rowscratch[wave * 32 + mt * 16 + quad * 4 + r] = rsum[mt][r];
    }
    __syncthreads();
#pragma unroll
    for (int mt = 0; mt < 2; ++mt)
#pragma unroll
        for (int r = 0; r < 4; ++r) {
            const int row = mt * 16 + quad * 4 + r;
            const float st = rowscratch[row] + rowscratch[32 + row]
                           + rowscratch[64 + row] + rowscratch[96 + row];
            if (wave == 0 && c16 == 0) inv_lds[row] = 1.0f / st;
#pragma unroll
            for (int nt = 0; nt < 4; ++nt)
                lds_buf[row * ATTN_STRIDE + n0l + nt * 16 + c16] = f2h(accl[mt][nt][r]);
        }
    __syncthreads();

    // ========== Phase 4: weighted = attn @ lt (K=256) =====================
    f32x4 accw[2][8];
#pragma unroll
    for (int mt = 0; mt < 2; ++mt)
#pragma unroll
        for (int nt = 0; nt < 8; ++nt) accw[mt][nt] = z4;
    {
        const unsigned short* ab = lds_buf + c16 * ATTN_STRIDE + quad * 8;
        const short8* lt8 = (const short8*)(const void*)lt_f + lane;
        for (int kt = 0; kt < 8; ++kt) {
            const int kk = kt * 32;
            short8 a0 = *(const short8*)(const void*)(ab + kk);
            short8 a1 = *(const short8*)(const void*)(ab + 16 * ATTN_STRIDE + kk);
#pragma unroll
            for (int nt = 0; nt < 8; ++nt) {
                short8 bfr = lt8[(((wave * 8 + nt) * 8) + kt) * 64];
                accw[0][nt] = MFMA_F16(a0, bfr, accw[0][nt]);
                accw[1][nt] = MFMA_F16(a1, bfr, accw[1][nt]);
            }
        }
    }

    // ========== Phase 5: fusion[b][c] += sum_rows it * weighted * invsum ==
    float invr[2][4];
#pragma unroll
    for (int mt = 0; mt < 2; ++mt)
#pragma unroll
        for (int r = 0; r < 4; ++r) invr[mt][r] = inv_lds[mt * 16 + quad * 4 + r];
#pragma unroll
    for (int nt = 0; nt < 8; ++nt) {
        const int col = n0 + nt * 16 + c16;
        const float bv = bi[col];
        float s = 0.f;
#pragma unroll
        for (int mt = 0; mt < 2; ++mt)
#pragma unroll
            for (int r = 0; r < 4; ++r)
                s += accw[mt][nt][r] * sigmoid_f(acci[mt][nt][r] + bv) * invr[mt][r];
        s += __shfl_xor(s, 16, 64);
        s += __shfl_xor(s, 32, 64);
        if (lane < 16) atomicAdd(&fusion[b * C_DIM + col], s);
    }
}

// ---------------------------------------------------------------------------
// Kernel 3: out[b][h] = sum_c fusion[b][c] * Wp[h][c]. 8 lanes per row,
// 128 B-contiguous Wp reads per 8-lane group. 384 blocks.
// ---------------------------------------------------------------------------
__global__ __launch_bounds__(256) void out_kernel(
    const float* __restrict__ fusion,
    const float* __restrict__ Wp,
    float* __restrict__ out)
{
    const int idx = blockIdx.x * 256 + threadIdx.x;
    const int R   = idx >> 3;        // 0..12287 = b*768 + h
    const int sub = idx & 7;
    const int bb  = R / H_DIM;
    const int h   = R - bb * H_DIM;
    const float* wp = Wp + (size_t)h * C_DIM;
    const float* f  = fusion + bb * C_DIM;
    float s = 0.f;
#pragma unroll
    for (int j = 0; j < 16; ++j) {
        const int c = j * 32 + sub * 4;
        float4 wv = *(const float4*)(const void*)(wp + c);
        float4 fv = *(const float4*)(const void*)(f + c);
        s += fv.x * wv.x + fv.y * wv.y + fv.z * wv.z + fv.w * wv.w;
    }
    s += __shfl_xor(s, 1, 64);
    s += __shfl_xor(s, 2, 64);
    s += __shfl_xor(s, 4, 64);
    if (sub == 0) out[R] = s;
}

extern "C" void kernel_launch(void* const* d_in, const int* in_sizes, int n_in,
                              void* d_out, int out_size, void* d_ws, size_t ws_size,
                              hipStream_t stream)
{
    const float* x    = (const float*)d_in[0];
    const float* lab  = (const float*)d_in[1];
    const float* Wi   = (const float*)d_in[2];
    const float* bi   = (const float*)d_in[3];
    const float* Wl   = (const float*)d_in[4];
    const float* bl   = (const float*)d_in[5];
    const float* Wia  = (const float*)d_in[6];
    const float* bia  = (const float*)d_in[7];
    const float* Wla  = (const float*)d_in[8];
    const float* bla  = (const float*)d_in[9];
    const float* ctx  = (const float*)d_in[10];
    const float* Wp   = (const float*)d_in[11];

    char* ws = (char*)d_ws;
    unsigned short* Wi_f  = (unsigned short*)(ws);               // frag f16, 768 KB
    unsigned short* Wia_f = (unsigned short*)(ws + 786432);      // frag f16, 768 KB
    unsigned short* la_f  = (unsigned short*)(ws + 1572864);     // frag f16, 256 KB
    unsigned short* lt_f  = (unsigned short*)(ws + 1835008);     // frag f16, 256 KB
    float* fusion         = (float*)(ws + 2097152);              // f32 [16][512], 32 KB

    (void)hipMemsetAsync(fusion, 0, B_DIM * C_DIM * sizeof(float), stream);
    prep_w<<<384, 256, 0, stream>>>(Wi, Wia, Wi_f, Wia_f);
    label_mfma<<<32, 256, 0, stream>>>(lab, Wl, bl, Wla, bla, ctx, la_f, lt_f);
    fused_main<<<(B_DIM * S_DIM) / 32, 256, 0, stream>>>(x, bi, bia, Wi_f, Wia_f, lt_f, la_f, fusion);
    out_kernel<<<384, 256, 0, stream>>>(fusion, Wp, (float*)d_out);
}

// Round 6
// 349.813 us; speedup vs baseline: 1.9197x; 1.3003x over previous
//
#include <hip/hip_runtime.h>

#define H_DIM 768
#define C_DIM 512
#define L_DIM 256
#define S_DIM 2048
#define B_DIM 16

#define IA_STRIDE 520   // 512 + 8: lane stride 1040B = 260 dw = 4 mod 32 banks
#define ATTN_STRIDE 264 // 256 + 8: lane stride 528B = 132 dw = 4 mod 32 banks

typedef __attribute__((ext_vector_type(8))) short short8;
typedef __attribute__((ext_vector_type(4))) float f32x4;
typedef __attribute__((ext_vector_type(2))) __fp16 half2v;   // cvt_pkrtz return type

#define MFMA_F16(a, b, c) __builtin_amdgcn_mfma_f32_16x16x32_f16((a), (b), (c), 0, 0, 0)

__device__ __forceinline__ unsigned short f2h(float f) {
    _Float16 h = (_Float16)f;
    return __builtin_bit_cast(unsigned short, h);
}
__device__ __forceinline__ float h2f(unsigned short u) {
    _Float16 h = __builtin_bit_cast(_Float16, u);
    return (float)h;
}
__device__ __forceinline__ float sigmoid_f(float x) { return 1.0f / (1.0f + __expf(-x)); }

// load 8 consecutive f32, convert to packed f16 frag via v_cvt_pkrtz
__device__ __forceinline__ short8 cvt8(const float* p) {
    const float4* q = (const float4*)(const void*)p;
    float4 u = q[0], v = q[1];
    half2v h0 = __builtin_amdgcn_cvt_pkrtz(u.x, u.y);
    half2v h1 = __builtin_amdgcn_cvt_pkrtz(u.z, u.w);
    half2v h2 = __builtin_amdgcn_cvt_pkrtz(v.x, v.y);
    half2v h3 = __builtin_amdgcn_cvt_pkrtz(v.z, v.w);
    int4 pk = { __builtin_bit_cast(int, h0), __builtin_bit_cast(int, h1),
                __builtin_bit_cast(int, h2), __builtin_bit_cast(int, h3) };
    return __builtin_bit_cast(short8, pk);
}

// ---------------------------------------------------------------------------
// Frag layouts (all B operands frag-packed; one wave frag load = 64 lanes x
// 16 B = 1 KB contiguous). kt-major within a wave's slice so each kt's nt-run
// is contiguous (8 KB) -> offset-immediate loads.
//   W  (n=c 32 ct, k=h 24 kt): frag = ((ct>>3)*24 + kt)*8 + (ct&7)
//   la (n=l 16 lt, k=c 16 kt): frag = ((lt>>2)*16 + kt)*4 + (lt&3)
//   lt (n=c 32 ct, k=l  8 kt): frag = ((ct>>3)*8  + kt)*8 + (ct&7)
//   element: lane = (n&15) | (((k>>3)&3)<<4), j = k&7; addr = (frag*64+lane)*8+j
// ---------------------------------------------------------------------------

// Kernel 0: repack Wi, Wia (f32 [C][H]) into frag-f16 layout.
__global__ __launch_bounds__(256) void prep_w(
    const float* __restrict__ Wi, const float* __restrict__ Wia,
    unsigned short* __restrict__ Wi_f, unsigned short* __restrict__ Wia_f)
{
    const int tid = blockIdx.x * 256 + threadIdx.x;
    const int m   = tid >= 49152;
    const int idx = tid - (m ? 49152 : 0);
    const int ct   = idx / 1536;          // 0..31
    const int rem  = idx - ct * 1536;
    const int kt   = rem >> 6;            // 0..23
    const int lane = rem & 63;
    const int row  = ct * 16 + (lane & 15);
    const int kcol = kt * 32 + (lane >> 4) * 8;
    const float* src = (m ? Wia : Wi) + (size_t)row * H_DIM + kcol;
    short8 v = cvt8(src);
    const int frag = ((ct >> 3) * 24 + kt) * 8 + (ct & 7);
    unsigned short* dst = (m ? Wia_f : Wi_f) + ((size_t)frag * 64 + lane) * 8;
    *(short8*)(void*)dst = v;
}

// ---------------------------------------------------------------------------
// Kernel 1: label-side joint MFMA GEMM. Grid 64 = 8 c-tiles(64) x 8 l-blocks(32).
// Epilogue scatter-writes la_f / lt_f in frag layout.
// ---------------------------------------------------------------------------
__global__ __launch_bounds__(256) void label_mfma(
    const float* __restrict__ lab,
    const float* __restrict__ Wl,  const float* __restrict__ bl,
    const float* __restrict__ Wla, const float* __restrict__ bla,
    const float* __restrict__ ctx,
    unsigned short* __restrict__ la_f,
    unsigned short* __restrict__ lt_f)
{
    const int tid  = threadIdx.x;
    const int wave = tid >> 6;
    const int lane = tid & 63;
    const int quad = lane >> 4;
    const int c16  = lane & 15;
    const int ct2  = blockIdx.x & 7;
    const int mh   = blockIdx.x >> 3;    // 0..7
    const int n0   = ct2 * 64 + wave * 16;
    const int l0   = mh * 32;

    const f32x4 z4 = {0.f, 0.f, 0.f, 0.f};
    f32x4 a1[2], a2[2];
#pragma unroll
    for (int mt = 0; mt < 2; ++mt) { a1[mt] = z4; a2[mt] = z4; }

    const float* lb  = lab + (size_t)(l0 + c16) * H_DIM + quad * 8;
    const float* wl  = Wl  + (size_t)(n0 + c16) * H_DIM + quad * 8;
    const float* wla = Wla + (size_t)(n0 + c16) * H_DIM + quad * 8;
    for (int kt = 0; kt < 24; ++kt) {
        const int kk = kt * 32;
        short8 b1 = cvt8(wl + kk);
        short8 b2 = cvt8(wla + kk);
#pragma unroll
        for (int mt = 0; mt < 2; ++mt) {
            short8 a = cvt8(lb + mt * 16 * H_DIM + kk);
            a1[mt] = MFMA_F16(a, b1, a1[mt]);
            a2[mt] = MFMA_F16(a, b2, a2[mt]);
        }
    }
    const int c = n0 + c16;
    const float blv = bl[c], blav = bla[c], cv = ctx[c];
#pragma unroll
    for (int mt = 0; mt < 2; ++mt)
#pragma unroll
        for (int r = 0; r < 4; ++r) {
            const int l = l0 + mt * 16 + quad * 4 + r;
            const float ltv = sigmoid_f(a1[mt][r] + blv);
            const float lav = sigmoid_f(a2[mt][r] + blav) * cv;
            {   // lt_f: n=c, k=l
                const int ct = c >> 4, ktl = l >> 5;
                const int frag = ((ct >> 3) * 8 + ktl) * 8 + (ct & 7);
                const int ln = (c & 15) | (((l >> 3) & 3) << 4);
                lt_f[((size_t)frag * 64 + ln) * 8 + (l & 7)] = f2h(ltv);
            }
            {   // la_f: n=l, k=c
                const int lt = l >> 4, ktc = c >> 5;
                const int frag = ((lt >> 2) * 16 + ktc) * 4 + (lt & 3);
                const int ln = (l & 15) | (((c >> 3) & 3) << 4);
                la_f[((size_t)frag * 64 + ln) * 8 + (c & 7)] = f2h(lav);
            }
        }
}

// ---------------------------------------------------------------------------
// Kernel 2: fused main. One block = 32 rows of [B*S]. 4 waves, C/L-split.
// Sequential GEMMs keep peak live accumulators at 64 VGPRs ->
// __launch_bounds__(256,4) -> VGPR<=128 -> 4 waves/SIMD (m69 occupancy step).
// Phase 1: ia = sigmoid(x@Wia^T+bia) -> LDS.
// Phase 2: logits = ia @ la^T.   Phase 3: softmax (unnorm, keep 1/sum).
// Phase 4: weighted = attn @ lt; spill weighted*invsum to LDS as f16
//          (overlays dead ia/attn region; wave-private, no barrier needed
//          after the write).
// Phase 5: it = x@Wi^T recomputed (x is L2/LLC-hot), fusion + atomics.
// MFMA 16x16x32: A frag = A[m=lane&15][k=quad*8+j]; C/D: col=lane&15,
// row = quad*4 + reg.
// ---------------------------------------------------------------------------
__global__ __launch_bounds__(256, 4) void fused_main(
    const float* __restrict__ x,
    const float* __restrict__ bi,
    const float* __restrict__ bia,
    const unsigned short* __restrict__ Wi_f,
    const unsigned short* __restrict__ Wia_f,
    const unsigned short* __restrict__ lt_f,
    const unsigned short* __restrict__ la_f,
    float* __restrict__ fusion)                 // f32 [B][C]
{
    __shared__ unsigned short lds_buf[32 * IA_STRIDE]; // ia / attn(head) / wgt
    __shared__ float rowscratch[4 * 32];
    __shared__ float inv_lds[32];

    const int tid  = threadIdx.x;
    const int wave = tid >> 6;
    const int lane = tid & 63;
    const int quad = lane >> 4;
    const int c16  = lane & 15;

    const int row0 = blockIdx.x * 32;
    const int b    = row0 >> 11;   // / 2048

    const f32x4 z4 = {0.f, 0.f, 0.f, 0.f};
    const int n0 = wave * 128;     // C-column split

    const float* xb = x + (size_t)(row0 + c16) * H_DIM + quad * 8;

    // ========== Phase 1: ia = x@Wia^T (K=768), sigmoid -> LDS =============
    {
        f32x4 acc[2][8];
#pragma unroll
        for (int mt = 0; mt < 2; ++mt)
#pragma unroll
            for (int nt = 0; nt < 8; ++nt) acc[mt][nt] = z4;
        const short8* wa8 = (const short8*)(const void*)Wia_f + (size_t)wave * 192 * 64 + lane;
        for (int kt = 0; kt < 24; ++kt) {
            short8 a0 = cvt8(xb + kt * 32);
            short8 a1 = cvt8(xb + 16 * H_DIM + kt * 32);
#pragma unroll
            for (int nt = 0; nt < 8; ++nt) {
                short8 ba = wa8[(kt * 8 + nt) * 64];
                acc[0][nt] = MFMA_F16(a0, ba, acc[0][nt]);
                acc[1][nt] = MFMA_F16(a1, ba, acc[1][nt]);
            }
        }
#pragma unroll
        for (int nt = 0; nt < 8; ++nt) {
            const int col = n0 + nt * 16 + c16;
            const float bv = bia[col];
#pragma unroll
            for (int mt = 0; mt < 2; ++mt)
#pragma unroll
                for (int r = 0; r < 4; ++r) {
                    const int row = mt * 16 + quad * 4 + r;
                    lds_buf[row * IA_STRIDE + col] = f2h(sigmoid_f(acc[mt][nt][r] + bv));
                }
        }
    }
    __syncthreads();

    // ========== Phase 2: logits = ia @ la^T (K=512) =======================
    const int n0l = wave * 64;   // L-column split
    f32x4 accl[2][4];
#pragma unroll
    for (int mt = 0; mt < 2; ++mt)
#pragma unroll
        for (int nt = 0; nt < 4; ++nt) accl[mt][nt] = z4;
    {
        const unsigned short* ab = lds_buf + c16 * IA_STRIDE + quad * 8;
        const short8* la8 = (const short8*)(const void*)la_f + (size_t)wave * 64 * 64 + lane;
        for (int kt = 0; kt < 16; ++kt) {
            const int kk = kt * 32;
            short8 a0 = *(const short8*)(const void*)(ab + kk);
            short8 a1 = *(const short8*)(const void*)(ab + 16 * IA_STRIDE + kk);
#pragma unroll
            for (int nt = 0; nt < 4; ++nt) {
                short8 bfr = la8[(kt * 4 + nt) * 64];
                accl[0][nt] = MFMA_F16(a0, bfr, accl[0][nt]);
                accl[1][nt] = MFMA_F16(a1, bfr, accl[1][nt]);
            }
        }
    }
    __syncthreads();   // all ia reads complete; lds_buf reusable

    // ========== Phase 3: softmax over L (unnormalized; keep 1/sum) ========
    float rmax[2][4];
#pragma unroll
    for (int mt = 0; mt < 2; ++mt)
#pragma unroll
        for (int r = 0; r < 4; ++r) {
            float m = accl[mt][0][r];
#pragma unroll
            for (int nt = 1; nt < 4; ++nt) m = fmaxf(m, accl[mt][nt][r]);
#pragma unroll
            for (int off = 1; off < 16; off <<= 1) m = fmaxf(m, __shfl_xor(m, off, 64));
            rmax[mt][r] = m;
        }
    if (c16 == 0) {
#pragma unroll
        for (int mt = 0; mt < 2; ++mt)
#pragma unroll
            for (int r = 0; r < 4; ++r)
                rowscratch[wave * 32 + mt * 16 + quad * 4 + r] = rmax[mt][r];
    }
    __syncthreads();
    float rsum[2][4];
#pragma unroll
    for (int mt = 0; mt < 2; ++mt)
#pragma unroll
        for (int r = 0; r < 4; ++r) {
            const int row = mt * 16 + quad * 4 + r;
            float gm = rowscratch[row];
#pragma unroll
            for (int w = 1; w < 4; ++w) gm = fmaxf(gm, rowscratch[w * 32 + row]);
            float s = 0.f;
#pragma unroll
            for (int nt = 0; nt < 4; ++nt) {
                float e = __expf(accl[mt][nt][r] - gm);
                accl[mt][nt][r] = e;
                s += e;
            }
#pragma unroll
            for (int off = 1; off < 16; off <<= 1) s += __shfl_xor(s, off, 64);
            rsum[mt][r] = s;
        }
    __syncthreads();   // maxima consumed
    if (c16 == 0) {
#pragma unroll
        for (int mt = 0; mt < 2; ++mt)
#pragma unroll
            for (int r = 0; r < 4; ++r)
                rowscratch[wave * 32 + mt * 16 + quad * 4 + r] = rsum[mt][r];
    }
    __syncthreads();
#pragma unroll
    for (int mt = 0; mt < 2; ++mt)
#pragma unroll
        for (int r = 0; r < 4; ++r) {
            const int row = mt * 16 + quad * 4 + r;
            const float st = rowscratch[row] + rowscratch[32 + row]
                           + rowscratch[64 + row] + rowscratch[96 + row];
            if (wave == 0 && c16 == 0) inv_lds[row] = 1.0f / st;
#pragma unroll
            for (int nt = 0; nt < 4; ++nt)
                lds_buf[row * ATTN_STRIDE + n0l + nt * 16 + c16] = f2h(accl[mt][nt][r]);
        }
    __syncthreads();

    // ========== Phase 4: weighted = attn @ lt (K=256) =====================
    f32x4 accw[2][8];
#pragma unroll
    for (int mt = 0; mt < 2; ++mt)
#pragma unroll
        for (int nt = 0; nt < 8; ++nt) accw[mt][nt] = z4;
    {
        const unsigned short* ab = lds_buf + c16 * ATTN_STRIDE + quad * 8;
        const short8* lt8 = (const short8*)(const void*)lt_f + (size_t)wave * 64 * 64 + lane;
        for (int kt = 0; kt < 8; ++kt) {
            const int kk = kt * 32;
            short8 a0 = *(const short8*)(const void*)(ab + kk);
            short8 a1 = *(const short8*)(const void*)(ab + 16 * ATTN_STRIDE + kk);
#pragma unroll
            for (int nt = 0; nt < 8; ++nt) {
                short8 bfr = lt8[(kt * 8 + nt) * 64];
                accw[0][nt] = MFMA_F16(a0, bfr, accw[0][nt]);
                accw[1][nt] = MFMA_F16(a1, bfr, accw[1][nt]);
            }
        }
    }
    __syncthreads();   // all attn reads complete; lds_buf reusable for wgt

    // spill wgt = weighted * invsum to LDS (f16); wave-private region
    {
        float invr[2][4];
#pragma unroll
        for (int mt = 0; mt < 2; ++mt)
#pragma unroll
            for (int r = 0; r < 4; ++r) invr[mt][r] = inv_lds[mt * 16 + quad * 4 + r];
#pragma unroll
        for (int nt = 0; nt < 8; ++nt) {
            const int col = n0 + nt * 16 + c16;
#pragma unroll
            for (int mt = 0; mt < 2; ++mt)
#pragma unroll
                for (int r = 0; r < 4; ++r) {
                    const int row = mt * 16 + quad * 4 + r;
                    lds_buf[row * IA_STRIDE + col] = f2h(accw[mt][nt][r] * invr[mt][r]);
                }
        }
    }
    // no barrier: phase 5 reads only this wave's own cols/rows

    // ========== Phase 5: it = x@Wi^T (recompute), fusion + atomics ========
    {
        f32x4 acc[2][8];
#pragma unroll
        for (int mt = 0; mt < 2; ++mt)
#pragma unroll
            for (int nt = 0; nt < 8; ++nt) acc[mt][nt] = z4;
        const short8* wi8 = (const short8*)(const void*)Wi_f + (size_t)wave * 192 * 64 + lane;
        for (int kt = 0; kt < 24; ++kt) {
            short8 a0 = cvt8(xb + kt * 32);
            short8 a1 = cvt8(xb + 16 * H_DIM + kt * 32);
#pragma unroll
            for (int nt = 0; nt < 8; ++nt) {
                short8 bw = wi8[(kt * 8 + nt) * 64];
                acc[0][nt] = MFMA_F16(a0, bw, acc[0][nt]);
                acc[1][nt] = MFMA_F16(a1, bw, acc[1][nt]);
            }
        }
#pragma unroll
        for (int nt = 0; nt < 8; ++nt) {
            const int col = n0 + nt * 16 + c16;
            const float bv = bi[col];
            float s = 0.f;
#pragma unroll
            for (int mt = 0; mt < 2; ++mt)
#pragma unroll
                for (int r = 0; r < 4; ++r) {
                    const int row = mt * 16 + quad * 4 + r;
                    s += h2f(lds_buf[row * IA_STRIDE + col]) * sigmoid_f(acc[mt][nt][r] + bv);
                }
            s += __shfl_xor(s, 16, 64);
            s += __shfl_xor(s, 32, 64);
            if (lane < 16) atomicAdd(&fusion[b * C_DIM + col], s);
        }
    }
}

// ---------------------------------------------------------------------------
// Kernel 3: out[b][h] = sum_c fusion[b][c] * Wp[h][c]. 8 lanes per row.
// ---------------------------------------------------------------------------
__global__ __launch_bounds__(256) void out_kernel(
    const float* __restrict__ fusion,
    const float* __restrict__ Wp,
    float* __restrict__ out)
{
    const int idx = blockIdx.x * 256 + threadIdx.x;
    const int R   = idx >> 3;
    const int sub = idx & 7;
    const int bb  = R / H_DIM;
    const int h   = R - bb * H_DIM;
    const float* wp = Wp + (size_t)h * C_DIM;
    const float* f  = fusion + bb * C_DIM;
    float s = 0.f;
#pragma unroll
    for (int j = 0; j < 16; ++j) {
        const int c = j * 32 + sub * 4;
        float4 wv = *(const float4*)(const void*)(wp + c);
        float4 fv = *(const float4*)(const void*)(f + c);
        s += fv.x * wv.x + fv.y * wv.y + fv.z * wv.z + fv.w * wv.w;
    }
    s += __shfl_xor(s, 1, 64);
    s += __shfl_xor(s, 2, 64);
    s += __shfl_xor(s, 4, 64);
    if (sub == 0) out[R] = s;
}

extern "C" void kernel_launch(void* const* d_in, const int* in_sizes, int n_in,
                              void* d_out, int out_size, void* d_ws, size_t ws_size,
                              hipStream_t stream)
{
    const float* x    = (const float*)d_in[0];
    const float* lab  = (const float*)d_in[1];
    const float* Wi   = (const float*)d_in[2];
    const float* bi   = (const float*)d_in[3];
    const float* Wl   = (const float*)d_in[4];
    const float* bl   = (const float*)d_in[5];
    const float* Wia  = (const float*)d_in[6];
    const float* bia  = (const float*)d_in[7];
    const float* Wla  = (const float*)d_in[8];
    const float* bla  = (const float*)d_in[9];
    const float* ctx  = (const float*)d_in[10];
    const float* Wp   = (const float*)d_in[11];

    char* ws = (char*)d_ws;
    unsigned short* Wi_f  = (unsigned short*)(ws);               // frag f16, 768 KB
    unsigned short* Wia_f = (unsigned short*)(ws + 786432);      // frag f16, 768 KB
    unsigned short* la_f  = (unsigned short*)(ws + 1572864);     // frag f16, 256 KB
    unsigned short* lt_f  = (unsigned short*)(ws + 1835008);     // frag f16, 256 KB
    float* fusion         = (float*)(ws + 2097152);              // f32 [16][512], 32 KB

    (void)hipMemsetAsync(fusion, 0, B_DIM * C_DIM * sizeof(float), stream);
    prep_w<<<384, 256, 0, stream>>>(Wi, Wia, Wi_f, Wia_f);
    label_mfma<<<64, 256, 0, stream>>>(lab, Wl, bl, Wla, bla, ctx, la_f, lt_f);
    fused_main<<<(B_DIM * S_DIM) / 32, 256, 0, stream>>>(x, bi, bia, Wi_f, Wia_f, lt_f, la_f, fusion);
    out_kernel<<<384, 256, 0, stream>>>(fusion, Wp, (float*)d_out);
}

// Round 7
// 332.359 us; speedup vs baseline: 2.0205x; 1.0525x over previous
//
#include <hip/hip_runtime.h>

#define H_DIM 768
#define C_DIM 512
#define L_DIM 256
#define S_DIM 2048
#define B_DIM 16

#define IA_STRIDE 520   // 512 + 8: lane stride 1040B = 260 dw = 4 mod 32 banks
#define ATTN_STRIDE 264 // 256 + 8: lane stride 528B = 132 dw = 4 mod 32 banks

typedef __attribute__((ext_vector_type(8))) short short8;
typedef __attribute__((ext_vector_type(4))) float f32x4;
typedef __attribute__((ext_vector_type(2))) __fp16 half2v;   // cvt_pkrtz return type

#define MFMA_F16(a, b, c) __builtin_amdgcn_mfma_f32_16x16x32_f16((a), (b), (c), 0, 0, 0)

__device__ __forceinline__ unsigned short f2h(float f) {
    _Float16 h = (_Float16)f;
    return __builtin_bit_cast(unsigned short, h);
}
__device__ __forceinline__ float h2f(unsigned short u) {
    _Float16 h = __builtin_bit_cast(_Float16, u);
    return (float)h;
}
__device__ __forceinline__ float sigmoid_f(float x) { return 1.0f / (1.0f + __expf(-x)); }

// load 8 consecutive f32, convert to packed f16 frag via v_cvt_pkrtz
__device__ __forceinline__ short8 cvt8(const float* p) {
    const float4* q = (const float4*)(const void*)p;
    float4 u = q[0], v = q[1];
    half2v h0 = __builtin_amdgcn_cvt_pkrtz(u.x, u.y);
    half2v h1 = __builtin_amdgcn_cvt_pkrtz(u.z, u.w);
    half2v h2 = __builtin_amdgcn_cvt_pkrtz(v.x, v.y);
    half2v h3 = __builtin_amdgcn_cvt_pkrtz(v.z, v.w);
    int4 pk = { __builtin_bit_cast(int, h0), __builtin_bit_cast(int, h1),
                __builtin_bit_cast(int, h2), __builtin_bit_cast(int, h3) };
    return __builtin_bit_cast(short8, pk);
}

// ---------------------------------------------------------------------------
// Frag layouts (one wave frag load = 64 lanes x 16 B = 1 KB contiguous):
//   B operand M[n][k]: lane = (n&15) | (((k>>3)&3)<<4), j = k&7
//     W  (n 32 ct, k 24 kt): frag = ((ct>>3)*24 + kt)*8 + (ct&7)
//     la (n 16 lt, k 16 kt): frag = ((lt>>2)*16 + kt)*4 + (lt&3)
//     lt (n 32 ct, k  8 kt): frag = ((ct>>3)*8  + kt)*8 + (ct&7)
//   A operand x[m][k]: lane = (m&15) | (((k>>3)&3)<<4), j = k&7
//     x  (m 2048 mt, k 24 kt): frag = mt*24 + kt
// ---------------------------------------------------------------------------

// Kernel 0a: repack Wi, Wia, Wl, Wla (f32 [C][H]) into frag-f16 layout.
__global__ __launch_bounds__(256) void prep_w(
    const float* __restrict__ Wi, const float* __restrict__ Wia,
    const float* __restrict__ Wl, const float* __restrict__ Wla,
    unsigned short* __restrict__ Wi_f, unsigned short* __restrict__ Wia_f,
    unsigned short* __restrict__ Wl_f, unsigned short* __restrict__ Wla_f)
{
    const int tid = blockIdx.x * 256 + threadIdx.x;   // over 4*49152
    const int m   = tid / 49152;
    const int idx = tid - m * 49152;
    const int ct   = idx / 1536;          // 0..31
    const int rem  = idx - ct * 1536;
    const int kt   = rem >> 6;            // 0..23
    const int lane = rem & 63;
    const int row  = ct * 16 + (lane & 15);
    const int kcol = kt * 32 + (lane >> 4) * 8;
    const float* src = (m == 0 ? Wi : (m == 1 ? Wia : (m == 2 ? Wl : Wla)));
    unsigned short* dst = (m == 0 ? Wi_f : (m == 1 ? Wia_f : (m == 2 ? Wl_f : Wla_f)));
    short8 v = cvt8(src + (size_t)row * H_DIM + kcol);
    const int frag = ((ct >> 3) * 24 + kt) * 8 + (ct & 7);
    *(short8*)(void*)(dst + ((size_t)frag * 64 + lane) * 8) = v;
}

// Kernel 0b: pre-convert x (f32 [32768][768]) to f16 A-frag-packed layout.
__global__ __launch_bounds__(256) void prep_x(
    const float* __restrict__ x, unsigned short* __restrict__ x_f)
{
    const int tid = blockIdx.x * 256 + threadIdx.x;   // over 2048*24*64
    const int mt  = tid / 1536;
    const int rem = tid - mt * 1536;
    const int kt  = rem >> 6;
    const int lane = rem & 63;
    const int row = mt * 16 + (lane & 15);
    const int col = kt * 32 + (lane >> 4) * 8;
    short8 v = cvt8(x + (size_t)row * H_DIM + col);
    *(short8*)(void*)(x_f + ((size_t)(mt * 24 + kt) * 64 + lane) * 8) = v;
}

// ---------------------------------------------------------------------------
// Kernel 1: label-side joint MFMA GEMM, frag-packed W (contiguous B loads).
// Grid 64 = 8 c-tiles(64) x 8 l-blocks(32). Epilogue scatter-writes la_f/lt_f.
// ---------------------------------------------------------------------------
__global__ __launch_bounds__(256) void label_mfma(
    const float* __restrict__ lab,
    const unsigned short* __restrict__ Wl_f,  const float* __restrict__ bl,
    const unsigned short* __restrict__ Wla_f, const float* __restrict__ bla,
    const float* __restrict__ ctx,
    unsigned short* __restrict__ la_f,
    unsigned short* __restrict__ lt_f)
{
    const int tid  = threadIdx.x;
    const int wave = tid >> 6;
    const int lane = tid & 63;
    const int quad = lane >> 4;
    const int c16  = lane & 15;
    const int ct2  = blockIdx.x & 7;
    const int mh   = blockIdx.x >> 3;    // 0..7
    const int ct   = ct2 * 4 + wave;     // 0..31
    const int n0   = ct * 16;
    const int l0   = mh * 32;

    const f32x4 z4 = {0.f, 0.f, 0.f, 0.f};
    f32x4 a1[2], a2[2];
#pragma unroll
    for (int mt = 0; mt < 2; ++mt) { a1[mt] = z4; a2[mt] = z4; }

    const float* lb = lab + (size_t)(l0 + c16) * H_DIM + quad * 8;
    const short8* wl8  = (const short8*)(const void*)Wl_f  + ((size_t)(ct >> 3) * 24 * 8 + (ct & 7)) * 64 + lane;
    const short8* wla8 = (const short8*)(const void*)Wla_f + ((size_t)(ct >> 3) * 24 * 8 + (ct & 7)) * 64 + lane;
    for (int kt = 0; kt < 24; ++kt) {
        short8 b1 = wl8[kt * 8 * 64];
        short8 b2 = wla8[kt * 8 * 64];
#pragma unroll
        for (int mt = 0; mt < 2; ++mt) {
            short8 a = cvt8(lb + mt * 16 * H_DIM + kt * 32);
            a1[mt] = MFMA_F16(a, b1, a1[mt]);
            a2[mt] = MFMA_F16(a, b2, a2[mt]);
        }
    }
    const int c = n0 + c16;
    const float blv = bl[c], blav = bla[c], cv = ctx[c];
#pragma unroll
    for (int mt = 0; mt < 2; ++mt)
#pragma unroll
        for (int r = 0; r < 4; ++r) {
            const int l = l0 + mt * 16 + quad * 4 + r;
            const float ltv = sigmoid_f(a1[mt][r] + blv);
            const float lav = sigmoid_f(a2[mt][r] + blav) * cv;
            {   // lt_f: n=c, k=l
                const int ctc = c >> 4, ktl = l >> 5;
                const int frag = ((ctc >> 3) * 8 + ktl) * 8 + (ctc & 7);
                const int ln = (c & 15) | (((l >> 3) & 3) << 4);
                lt_f[((size_t)frag * 64 + ln) * 8 + (l & 7)] = f2h(ltv);
            }
            {   // la_f: n=l, k=c
                const int lt = l >> 4, ktc = c >> 5;
                const int frag = ((lt >> 2) * 16 + ktc) * 4 + (lt & 3);
                const int ln = (l & 15) | (((c >> 3) & 3) << 4);
                la_f[((size_t)frag * 64 + ln) * 8 + (c & 7)] = f2h(lav);
            }
        }
}

// ---------------------------------------------------------------------------
// Kernel 2: fused main. One block = 32 rows of [B*S]. 4 waves, C/L-split.
// XF=true: A-frags from pre-packed f16 x_f (one 16 B load, no cvt);
// XF=false: cvt8 from f32 x (ws too small fallback).
// Sequential GEMMs keep peak live accumulators at 64 regs; (256,4) ->
// combined regs <=128 -> 4 waves/SIMD (LDS-capped at 4 blocks/CU).
// ---------------------------------------------------------------------------
template<bool XF>
__global__ __launch_bounds__(256, 4) void fused_main(
    const unsigned short* __restrict__ x_f,     // A-frag f16 (XF only)
    const float* __restrict__ x,                // f32 (fallback only)
    const float* __restrict__ bi,
    const float* __restrict__ bia,
    const unsigned short* __restrict__ Wi_f,
    const unsigned short* __restrict__ Wia_f,
    const unsigned short* __restrict__ lt_f,
    const unsigned short* __restrict__ la_f,
    float* __restrict__ fusion)                 // f32 [B][C]
{
    __shared__ unsigned short lds_buf[32 * IA_STRIDE]; // ia / attn(head) / wgt
    __shared__ float rowscratch[4 * 32];
    __shared__ float inv_lds[32];

    const int tid  = threadIdx.x;
    const int wave = tid >> 6;
    const int lane = tid & 63;
    const int quad = lane >> 4;
    const int c16  = lane & 15;

    const int row0 = blockIdx.x * 32;
    const int b    = row0 >> 11;   // / 2048

    const f32x4 z4 = {0.f, 0.f, 0.f, 0.f};
    const int n0 = wave * 128;     // C-column split

    const float*  xb  = x + (size_t)(row0 + c16) * H_DIM + quad * 8;
    const short8* xf8 = (const short8*)(const void*)x_f + ((size_t)blockIdx.x * 2 * 24) * 64 + lane;

    // ========== Phase 1: ia = x@Wia^T (K=768), sigmoid -> LDS =============
    {
        f32x4 acc[2][8];
#pragma unroll
        for (int mt = 0; mt < 2; ++mt)
#pragma unroll
            for (int nt = 0; nt < 8; ++nt) acc[mt][nt] = z4;
        const short8* wa8 = (const short8*)(const void*)Wia_f + (size_t)wave * 192 * 64 + lane;
        for (int kt = 0; kt < 24; ++kt) {
            short8 a0, a1;
            if constexpr (XF) { a0 = xf8[kt * 64]; a1 = xf8[(24 + kt) * 64]; }
            else { a0 = cvt8(xb + kt * 32); a1 = cvt8(xb + 16 * H_DIM + kt * 32); }
#pragma unroll
            for (int nt = 0; nt < 8; ++nt) {
                short8 ba = wa8[(kt * 8 + nt) * 64];
                acc[0][nt] = MFMA_F16(a0, ba, acc[0][nt]);
                acc[1][nt] = MFMA_F16(a1, ba, acc[1][nt]);
            }
        }
#pragma unroll
        for (int nt = 0; nt < 8; ++nt) {
            const int col = n0 + nt * 16 + c16;
            const float bv = bia[col];
#pragma unroll
            for (int mt = 0; mt < 2; ++mt)
#pragma unroll
                for (int r = 0; r < 4; ++r) {
                    const int row = mt * 16 + quad * 4 + r;
                    lds_buf[row * IA_STRIDE + col] = f2h(sigmoid_f(acc[mt][nt][r] + bv));
                }
        }
    }
    __syncthreads();

    // ========== Phase 2: logits = ia @ la^T (K=512) =======================
    const int n0l = wave * 64;   // L-column split
    f32x4 accl[2][4];
#pragma unroll
    for (int mt = 0; mt < 2; ++mt)
#pragma unroll
        for (int nt = 0; nt < 4; ++nt) accl[mt][nt] = z4;
    {
        const unsigned short* ab = lds_buf + c16 * IA_STRIDE + quad * 8;
        const short8* la8 = (const short8*)(const void*)la_f + (size_t)wave * 64 * 64 + lane;
        for (int kt = 0; kt < 16; ++kt) {
            const int kk = kt * 32;
            short8 a0 = *(const short8*)(const void*)(ab + kk);
            short8 a1 = *(const short8*)(const void*)(ab + 16 * IA_STRIDE + kk);
#pragma unroll
            for (int nt = 0; nt < 4; ++nt) {
                short8 bfr = la8[(kt * 4 + nt) * 64];
                accl[0][nt] = MFMA_F16(a0, bfr, accl[0][nt]);
                accl[1][nt] = MFMA_F16(a1, bfr, accl[1][nt]);
            }
        }
    }
    __syncthreads();   // all ia reads complete; lds_buf reusable

    // ========== Phase 3: softmax over L (unnormalized; keep 1/sum) ========
    float rmax[2][4];
#pragma unroll
    for (int mt = 0; mt < 2; ++mt)
#pragma unroll
        for (int r = 0; r < 4; ++r) {
            float m = accl[mt][0][r];
#pragma unroll
            for (int nt = 1; nt < 4; ++nt) m = fmaxf(m, accl[mt][nt][r]);
#pragma unroll
            for (int off = 1; off < 16; off <<= 1) m = fmaxf(m, __shfl_xor(m, off, 64));
            rmax[mt][r] = m;
        }
    if (c16 == 0) {
#pragma unroll
        for (int mt = 0; mt < 2; ++mt)
#pragma unroll
            for (int r = 0; r < 4; ++r)
                rowscratch[wave * 32 + mt * 16 + quad * 4 + r] = rmax[mt][r];
    }
    __syncthreads();
    float rsum[2][4];
#pragma unroll
    for (int mt = 0; mt < 2; ++mt)
#pragma unroll
        for (int r = 0; r < 4; ++r) {
            const int row = mt * 16 + quad * 4 + r;
            float gm = rowscratch[row];
#pragma unroll
            for (int w = 1; w < 4; ++w) gm = fmaxf(gm, rowscratch[w * 32 + row]);
            float s = 0.f;
#pragma unroll
            for (int nt = 0; nt < 4; ++nt) {
                float e = __expf(accl[mt][nt][r] - gm);
                accl[mt][nt][r] = e;
                s += e;
            }
#pragma unroll
            for (int off = 1; off < 16; off <<= 1) s += __shfl_xor(s, off, 64);
            rsum[mt][r] = s;
        }
    __syncthreads();   // maxima consumed
    if (c16 == 0) {
#pragma unroll
        for (int mt = 0; mt < 2; ++mt)
#pragma unroll
            for (int r = 0; r < 4; ++r)
                rowscratch[wave * 32 + mt * 16 + quad * 4 + r] = rsum[mt][r];
    }
    __syncthreads();
#pragma unroll
    for (int mt = 0; mt < 2; ++mt)
#pragma unroll
        for (int r = 0; r < 4; ++r) {
            const int row = mt * 16 + quad * 4 + r;
            const float st = rowscratch[row] + rowscratch[32 + row]
                           + rowscratch[64 + row] + rowscratch[96 + row];
            if (wave == 0 && c16 == 0) inv_lds[row] = 1.0f / st;
#pragma unroll
            for (int nt = 0; nt < 4; ++nt)
                lds_buf[row * ATTN_STRIDE + n0l + nt * 16 + c16] = f2h(accl[mt][nt][r]);
        }
    __syncthreads();

    // ========== Phase 4: weighted = attn @ lt (K=256) =====================
    f32x4 accw[2][8];
#pragma unroll
    for (int mt = 0; mt < 2; ++mt)
#pragma unroll
        for (int nt = 0; nt < 8; ++nt) accw[mt][nt] = z4;
    {
        const unsigned short* ab = lds_buf + c16 * ATTN_STRIDE + quad * 8;
        const short8* lt8 = (const short8*)(const void*)lt_f + (size_t)wave * 64 * 64 + lane;
        for (int kt = 0; kt < 8; ++kt) {
            const int kk = kt * 32;
            short8 a0 = *(const short8*)(const void*)(ab + kk);
            short8 a1 = *(const short8*)(const void*)(ab + 16 * ATTN_STRIDE + kk);
#pragma unroll
            for (int nt = 0; nt < 8; ++nt) {
                short8 bfr = lt8[(kt * 8 + nt) * 64];
                accw[0][nt] = MFMA_F16(a0, bfr, accw[0][nt]);
                accw[1][nt] = MFMA_F16(a1, bfr, accw[1][nt]);
            }
        }
    }
    __syncthreads();   // all attn reads complete; lds_buf reusable for wgt

    // spill wgt = weighted * invsum to LDS (f16); wave-private region
    {
        float invr[2][4];
#pragma unroll
        for (int mt = 0; mt < 2; ++mt)
#pragma unroll
            for (int r = 0; r < 4; ++r) invr[mt][r] = inv_lds[mt * 16 + quad * 4 + r];
#pragma unroll
        for (int nt = 0; nt < 8; ++nt) {
            const int col = n0 + nt * 16 + c16;
#pragma unroll
            for (int mt = 0; mt < 2; ++mt)
#pragma unroll
                for (int r = 0; r < 4; ++r) {
                    const int row = mt * 16 + quad * 4 + r;
                    lds_buf[row * IA_STRIDE + col] = f2h(accw[mt][nt][r] * invr[mt][r]);
                }
        }
    }
    // no barrier: phase 5 reads only this wave's own cols/rows

    // ========== Phase 5: it = x@Wi^T (recompute), fusion + atomics ========
    {
        f32x4 acc[2][8];
#pragma unroll
        for (int mt = 0; mt < 2; ++mt)
#pragma unroll
            for (int nt = 0; nt < 8; ++nt) acc[mt][nt] = z4;
        const short8* wi8 = (const short8*)(const void*)Wi_f + (size_t)wave * 192 * 64 + lane;
        for (int kt = 0; kt < 24; ++kt) {
            short8 a0, a1;
            if constexpr (XF) { a0 = xf8[kt * 64]; a1 = xf8[(24 + kt) * 64]; }
            else { a0 = cvt8(xb + kt * 32); a1 = cvt8(xb + 16 * H_DIM + kt * 32); }
#pragma unroll
            for (int nt = 0; nt < 8; ++nt) {
                short8 bw = wi8[(kt * 8 + nt) * 64];
                acc[0][nt] = MFMA_F16(a0, bw, acc[0][nt]);
                acc[1][nt] = MFMA_F16(a1, bw, acc[1][nt]);
            }
        }
#pragma unroll
        for (int nt = 0; nt < 8; ++nt) {
            const int col = n0 + nt * 16 + c16;
            const float bv = bi[col];
            float s = 0.f;
#pragma unroll
            for (int mt = 0; mt < 2; ++mt)
#pragma unroll
                for (int r = 0; r < 4; ++r) {
                    const int row = mt * 16 + quad * 4 + r;
                    s += h2f(lds_buf[row * IA_STRIDE + col]) * sigmoid_f(acc[mt][nt][r] + bv);
                }
            s += __shfl_xor(s, 16, 64);
            s += __shfl_xor(s, 32, 64);
            if (lane < 16) atomicAdd(&fusion[b * C_DIM + col], s);
        }
    }
}

// ---------------------------------------------------------------------------
// Kernel 3: out[b][h] = sum_c fusion[b][c] * Wp[h][c]. 8 lanes per row.
// ---------------------------------------------------------------------------
__global__ __launch_bounds__(256) void out_kernel(
    const float* __restrict__ fusion,
    const float* __restrict__ Wp,
    float* __restrict__ out)
{
    const int idx = blockIdx.x * 256 + threadIdx.x;
    const int R   = idx >> 3;
    const int sub = idx & 7;
    const int bb  = R / H_DIM;
    const int h   = R - bb * H_DIM;
    const float* wp = Wp + (size_t)h * C_DIM;
    const float* f  = fusion + bb * C_DIM;
    float s = 0.f;
#pragma unroll
    for (int j = 0; j < 16; ++j) {
        const int c = j * 32 + sub * 4;
        float4 wv = *(const float4*)(const void*)(wp + c);
        float4 fv = *(const float4*)(const void*)(f + c);
        s += fv.x * wv.x + fv.y * wv.y + fv.z * wv.z + fv.w * wv.w;
    }
    s += __shfl_xor(s, 1, 64);
    s += __shfl_xor(s, 2, 64);
    s += __shfl_xor(s, 4, 64);
    if (sub == 0) out[R] = s;
}

extern "C" void kernel_launch(void* const* d_in, const int* in_sizes, int n_in,
                              void* d_out, int out_size, void* d_ws, size_t ws_size,
                              hipStream_t stream)
{
    const float* x    = (const float*)d_in[0];
    const float* lab  = (const float*)d_in[1];
    const float* Wi   = (const float*)d_in[2];
    const float* bi   = (const float*)d_in[3];
    const float* Wl   = (const float*)d_in[4];
    const float* bl   = (const float*)d_in[5];
    const float* Wia  = (const float*)d_in[6];
    const float* bia  = (const float*)d_in[7];
    const float* Wla  = (const float*)d_in[8];
    const float* bla  = (const float*)d_in[9];
    const float* ctx  = (const float*)d_in[10];
    const float* Wp   = (const float*)d_in[11];

    char* ws = (char*)d_ws;
    unsigned short* Wi_f  = (unsigned short*)(ws);               // 768 KB
    unsigned short* Wia_f = (unsigned short*)(ws + 786432);      // 768 KB
    unsigned short* Wl_f  = (unsigned short*)(ws + 1572864);     // 768 KB
    unsigned short* Wla_f = (unsigned short*)(ws + 2359296);     // 768 KB
    unsigned short* la_f  = (unsigned short*)(ws + 3145728);     // 256 KB
    unsigned short* lt_f  = (unsigned short*)(ws + 3407872);     // 256 KB
    float* fusion         = (float*)(ws + 3670016);              // 32 KB
    unsigned short* x_f   = (unsigned short*)(ws + 3702784);     // 48 MB (optional)
    const size_t NEED_XF  = 3702784 + (size_t)32768 * 768 * 2;   // ~51.5 MB

    (void)hipMemsetAsync(fusion, 0, B_DIM * C_DIM * sizeof(float), stream);
    prep_w<<<768, 256, 0, stream>>>(Wi, Wia, Wl, Wla, Wi_f, Wia_f, Wl_f, Wla_f);
    label_mfma<<<64, 256, 0, stream>>>(lab, Wl_f, bl, Wla_f, bla, ctx, la_f, lt_f);
    if (ws_size >= NEED_XF) {
        prep_x<<<12288, 256, 0, stream>>>(x, x_f);
        fused_main<true><<<(B_DIM * S_DIM) / 32, 256, 0, stream>>>(
            x_f, x, bi, bia, Wi_f, Wia_f, lt_f, la_f, fusion);
    } else {
        fused_main<false><<<(B_DIM * S_DIM) / 32, 256, 0, stream>>>(
            nullptr, x, bi, bia, Wi_f, Wia_f, lt_f, la_f, fusion);
    }
    out_kernel<<<384, 256, 0, stream>>>(fusion, Wp, (float*)d_out);
}